// Round 2
// baseline (810.904 us; speedup 1.0000x reference)
//
#include <hip/hip_runtime.h>
#include <hip/hip_bf16.h>
#include <hip/hip_cooperative_groups.h>

namespace cg = cooperative_groups;

#define NPIX 4096
#define FEAT 128
#define LAT 64
#define BS 64
#define NSTEPS 6

// flat f32 output offsets (log_m_k, log_s_k, c_f, delta, seeds)
#define OFF_LOGM  0u
#define OFF_LOGS  1835008u
#define OFF_CF    3670016u
#define OFF_DELTA 20447232u
#define OFF_SEEDS 20971520u

typedef float f32x4 __attribute__((ext_vector_type(4)));
typedef short s16x8 __attribute__((ext_vector_type(8)));

__device__ __forceinline__ void amax_comb(float& bv, int& bi, float v, int i) {
    if (v > bv || (v == bv && i < bi)) { bv = v; bi = i; }
}

__device__ __forceinline__ short f2bf_rne(float r) {
    __hip_bfloat16 h = __float2bfloat16(r);
    return __builtin_bit_cast(short, h);
}

// split f32 into bf16 hi (truncated -> exact residual) + bf16 lo (RNE of residual)
__device__ __forceinline__ void split2(float v, short& hi, short& lo) {
    unsigned u = __builtin_bit_cast(unsigned, v);
    hi = (short)(u >> 16);
    float hf = __builtin_bit_cast(float, u & 0xFFFF0000u);
    lo = f2bf_rne(v - hf);
}

// ---------------------------------------------------------------------------
// K1: 1x1 conv via split-bf16 MFMA. block = 256 thr (4 waves); each wave:
// all 64 outputs x 64 pixels. grid = 64 batches * 16 tiles (256 px) = 1024.
// ---------------------------------------------------------------------------
__global__ __launch_bounds__(256, 2) void conv_mfma(
    const float* __restrict__ x, const float* __restrict__ rand_pixel,
    const float* __restrict__ w, const float* __restrict__ bias,
    const float* __restrict__ gate_p, float* __restrict__ out,
    float* __restrict__ pval, int* __restrict__ pidx)
{
    __shared__ __align__(16) short Whi[64][136];  // pitch 136 elems = 272B (16B aligned rows)
    __shared__ __align__(16) short Wlo[64][136];
    __shared__ float sbias[64];

    const int tid  = threadIdx.x;
    const int b    = blockIdx.x >> 4;
    const int tile = blockIdx.x & 15;
    const int p0   = tile * 256;
    const int lane = tid & 63;
    const int wv   = tid >> 6;       // wave 0..3
    const int l15  = lane & 15;
    const int lg   = lane >> 4;      // 0..3

    const float gate = gate_p[0];

    // stage gate*W as split bf16 hi/lo, original [o][f] layout
    #pragma unroll
    for (int i = 0; i < 8; ++i) {
        int q = i * 256 + tid;           // quad 0..2047 (coalesced)
        int o = q >> 5;                  // 32 quads per 128-f row
        int f = (q & 31) * 4;
        float4 wq = *(const float4*)(w + o * 128 + f);
        short h0, l0, h1, l1, h2, l2, h3, l3;
        split2(gate * wq.x, h0, l0);
        split2(gate * wq.y, h1, l1);
        split2(gate * wq.z, h2, l2);
        split2(gate * wq.w, h3, l3);
        *(short4*)&Whi[o][f] = make_short4(h0, h1, h2, h3);
        *(short4*)&Wlo[o][f] = make_short4(l0, l1, l2, l3);
    }
    if (tid < 64) sbias[tid] = gate * bias[tid];
    __syncthreads();

    f32x4 acc[4][4];
    #pragma unroll
    for (int og = 0; og < 4; ++og)
        #pragma unroll
        for (int pg = 0; pg < 4; ++pg)
            acc[og][pg] = (f32x4){0.f, 0.f, 0.f, 0.f};

    const float* xb = x + (size_t)b * FEAT * NPIX + p0 + wv * 64;

    #pragma unroll
    for (int kc = 0; kc < 4; ++kc) {
        // A fragments (weights) for this K chunk: lane = out l15 within og, k = 8*lg+e
        s16x8 Ah[4], Al[4];
        #pragma unroll
        for (int og = 0; og < 4; ++og) {
            Ah[og] = *(const s16x8*)&Whi[og * 16 + l15][kc * 32 + lg * 8];
            Al[og] = *(const s16x8*)&Wlo[og * 16 + l15][kc * 32 + lg * 8];
        }
        #pragma unroll
        for (int pg = 0; pg < 4; ++pg) {
            const float* xp = xb + pg * 16 + l15;
            const int fb = kc * 32 + lg * 8;
            float xv[8];
            #pragma unroll
            for (int e = 0; e < 8; ++e)
                xv[e] = xp[(size_t)(fb + e) * NPIX];
            s16x8 Bh, Bl;
            #pragma unroll
            for (int e = 0; e < 8; ++e) {
                short h, l;
                split2(xv[e], h, l);
                Bh[e] = h; Bl[e] = l;
            }
            #pragma unroll
            for (int og = 0; og < 4; ++og) {
                acc[og][pg] = __builtin_amdgcn_mfma_f32_16x16x32_bf16(Ah[og], Bh, acc[og][pg], 0, 0, 0);
                acc[og][pg] = __builtin_amdgcn_mfma_f32_16x16x32_bf16(Ah[og], Bl, acc[og][pg], 0, 0, 0);
                acc[og][pg] = __builtin_amdgcn_mfma_f32_16x16x32_bf16(Al[og], Bh, acc[og][pg], 0, 0, 0);
            }
        }
    }

    // epilogue: D mapping col=l15 (pixel), row=4*lg+r (out within og*16)
    float* cf = out + OFF_CF + (size_t)b * LAT * NPIX;
    #pragma unroll
    for (int og = 0; og < 4; ++og) {
        #pragma unroll
        for (int pg = 0; pg < 4; ++pg) {
            #pragma unroll
            for (int r = 0; r < 4; ++r) {
                int o = og * 16 + lg * 4 + r;
                int p = p0 + wv * 64 + pg * 16 + l15;
                float v = acc[og][pg][r] + sbias[o];
                if (o == 62) {
                    out[OFF_DELTA + ((size_t)b * 2 + 0) * NPIX + p] = v;
                    v += (float)(-1.0 + 2.0 * (double)(p >> 6) / 63.0);
                } else if (o == 63) {
                    out[OFF_DELTA + ((size_t)b * 2 + 1) * NPIX + p] = v;
                    v += (float)(-1.0 + 2.0 * (double)(p & 63) / 63.0);
                }
                cf[(size_t)o * NPIX + p] = v;
            }
        }
    }

    // wave 0 extras: zero log_s_k[0], step-0 argmax partial (probs == rand_pixel)
    if (wv == 0) {
        *(float4*)(out + OFF_LOGS + (size_t)b * NPIX + p0 + lane * 4) =
            make_float4(0.f, 0.f, 0.f, 0.f);
        float4 rv = *(const float4*)(rand_pixel + (size_t)b * NPIX + p0 + lane * 4);
        int pb = p0 + lane * 4;
        float bv = rv.x; int bi = pb;
        if (rv.y > bv) { bv = rv.y; bi = pb + 1; }
        if (rv.z > bv) { bv = rv.z; bi = pb + 2; }
        if (rv.w > bv) { bv = rv.w; bi = pb + 3; }
        #pragma unroll
        for (int off = 32; off > 0; off >>= 1) {
            float ov = __shfl_down(bv, off, 64);
            int   oi = __shfl_down(bi, off, 64);
            amax_comb(bv, bi, ov, oi);
        }
        if (lane == 0) { pval[blockIdx.x] = bv; pidx[blockIdx.x] = bi; }
    }
}

// ---------------------------------------------------------------------------
// K2: all 6 clustering steps in ONE cooperative kernel. Thread = 1 pixel,
// c_f channels held in registers across steps. 1024 blocks co-resident.
// ---------------------------------------------------------------------------
__global__ __launch_bounds__(256, 4) void steps_coop(
    const float* __restrict__ rand_pixel, const float* __restrict__ log_sigma_p,
    float* __restrict__ out,
    float* pv0, int* pi0, float* pv1, int* pi1)
{
    cg::grid_group grid = cg::this_grid();
    __shared__ float s_mv[16];
    __shared__ int   s_mi[16];
    __shared__ float s_seed[LAT];
    __shared__ float s_rv[4];
    __shared__ int   s_ri[4];

    const int tid  = threadIdx.x;
    const int b    = blockIdx.x >> 4;
    const int tile = blockIdx.x & 15;
    const int p    = tile * 256 + tid;

    const float* cf = out + OFF_CF + (size_t)b * LAT * NPIX;
    float cr[LAT];
    #pragma unroll
    for (int c = 0; c < LAT; ++c) cr[c] = cf[(size_t)c * NPIX + p];

    const float rp    = rand_pixel[(size_t)b * NPIX + p];
    const float sigma = expf(log_sigma_p[0]);
    float ls = 0.f;

    for (int s = 0; s < NSTEPS; ++s) {
        float* pv = (s & 1) ? pv1 : pv0;
        int*   pi = (s & 1) ? pi1 : pi0;
        if (tid < 16) {
            s_mv[tid] = __hip_atomic_load(&pv[b * 16 + tid], __ATOMIC_ACQUIRE, __HIP_MEMORY_SCOPE_AGENT);
            s_mi[tid] = __hip_atomic_load(&pi[b * 16 + tid], __ATOMIC_ACQUIRE, __HIP_MEMORY_SCOPE_AGENT);
        }
        __syncthreads();
        float bv = -1.0f; int bi = 0;
        #pragma unroll
        for (int k = 0; k < 16; ++k) amax_comb(bv, bi, s_mv[k], s_mi[k]);
        if (tid < LAT) s_seed[tid] = cf[(size_t)tid * NPIX + bi];
        __syncthreads();
        if (tile == 0 && tid < LAT)
            out[OFF_SEEDS + ((size_t)s * BS + b) * LAT + tid] = s_seed[tid];

        float d2 = 0.f;
        #pragma unroll
        for (int c = 0; c < LAT; ++c) {
            float d = cr[c] - s_seed[c];
            d2 = fmaf(d, d, d2);
        }
        float dist  = sqrtf(fminf(fmaxf(d2, 1e-10f), 1e10f));
        float alpha = expf(-dist / sigma);
        alpha = fminf(fmaxf(alpha, 0.01f), 0.99f);
        float lm  = ls + logf(alpha);
        float lsn = ls + log1pf(-alpha);

        out[OFF_LOGM + ((size_t)s * BS + b) * NPIX + p]       = lm;
        out[OFF_LOGS + ((size_t)(s + 1) * BS + b) * NPIX + p] = lsn;
        ls = lsn;

        if (s == NSTEPS - 1) {
            out[OFF_LOGM + ((size_t)NSTEPS * BS + b) * NPIX + p] = lsn;
        } else {
            float* pvn = ((s + 1) & 1) ? pv1 : pv0;
            int*   pin = ((s + 1) & 1) ? pi1 : pi0;
            float prob = rp * expf(lsn);
            int   idx  = p;
            #pragma unroll
            for (int off = 32; off > 0; off >>= 1) {
                float ov = __shfl_down(prob, off, 64);
                int   oi = __shfl_down(idx, off, 64);
                amax_comb(prob, idx, ov, oi);
            }
            int lane = tid & 63, wid = tid >> 6;
            if (lane == 0) { s_rv[wid] = prob; s_ri[wid] = idx; }
            __syncthreads();
            if (tid == 0) {
                float fb = s_rv[0]; int fi = s_ri[0];
                #pragma unroll
                for (int k = 1; k < 4; ++k) amax_comb(fb, fi, s_rv[k], s_ri[k]);
                __hip_atomic_store(&pvn[b * 16 + tile], fb, __ATOMIC_RELEASE, __HIP_MEMORY_SCOPE_AGENT);
                __hip_atomic_store(&pin[b * 16 + tile], fi, __ATOMIC_RELEASE, __HIP_MEMORY_SCOPE_AGENT);
            }
            grid.sync();
        }
    }
}

// ---------------------------------------------------------------------------
// Fallback: per-step kernel (proven path) if cooperative launch unavailable.
// ---------------------------------------------------------------------------
__global__ __launch_bounds__(256, 4) void step_kernel(
    const float* __restrict__ rand_pixel, const float* __restrict__ log_sigma_p,
    float* __restrict__ out, float* __restrict__ pval, int* __restrict__ pidx,
    int step)
{
    __shared__ float s_seed[LAT];
    __shared__ float s_rv[4];
    __shared__ int   s_ri[4];

    const int tid  = threadIdx.x;
    const int b    = blockIdx.x >> 4;
    const int tile = blockIdx.x & 15;
    const int p    = tile * 256 + tid;

    float bv = -1.0f; int bi = 0;
    #pragma unroll
    for (int k = 0; k < 16; ++k) amax_comb(bv, bi, pval[b * 16 + k], pidx[b * 16 + k]);

    const float* cf = out + OFF_CF + (size_t)b * LAT * NPIX;
    if (tid < LAT) s_seed[tid] = cf[(size_t)tid * NPIX + bi];
    __syncthreads();

    if (tile == 0 && tid < LAT)
        out[OFF_SEEDS + ((size_t)step * BS + b) * LAT + tid] = s_seed[tid];

    float d2 = 0.f;
    #pragma unroll 16
    for (int c = 0; c < LAT; ++c) {
        float d = cf[(size_t)c * NPIX + p] - s_seed[c];
        d2 = fmaf(d, d, d2);
    }
    float dist  = sqrtf(fminf(fmaxf(d2, 1e-10f), 1e10f));
    float sigma = expf(log_sigma_p[0]);
    float alpha = expf(-dist / sigma);
    alpha = fminf(fmaxf(alpha, 0.01f), 0.99f);

    float ls  = out[OFF_LOGS + ((size_t)step * BS + b) * NPIX + p];
    float lm  = ls + logf(alpha);
    float lsn = ls + log1pf(-alpha);

    out[OFF_LOGM + ((size_t)step * BS + b) * NPIX + p]       = lm;
    out[OFF_LOGS + ((size_t)(step + 1) * BS + b) * NPIX + p] = lsn;
    if (step == NSTEPS - 1)
        out[OFF_LOGM + ((size_t)NSTEPS * BS + b) * NPIX + p] = lsn;

    if (step < NSTEPS - 1) {
        float prob = rand_pixel[(size_t)b * NPIX + p] * expf(lsn);
        int   idx  = p;
        #pragma unroll
        for (int off = 32; off > 0; off >>= 1) {
            float ov = __shfl_down(prob, off, 64);
            int   oi = __shfl_down(idx, off, 64);
            amax_comb(prob, idx, ov, oi);
        }
        int lane = tid & 63, wid = tid >> 6;
        if (lane == 0) { s_rv[wid] = prob; s_ri[wid] = idx; }
        __syncthreads();
        if (tid == 0) {
            float fb = s_rv[0]; int fi = s_ri[0];
            #pragma unroll
            for (int k = 1; k < 4; ++k) amax_comb(fb, fi, s_rv[k], s_ri[k]);
            pval[blockIdx.x] = fb; pidx[blockIdx.x] = fi;
        }
    }
}

extern "C" void kernel_launch(void* const* d_in, const int* in_sizes, int n_in,
                              void* d_out, int out_size, void* d_ws, size_t ws_size,
                              hipStream_t stream) {
    const float* x          = (const float*)d_in[0];
    const float* rand_pixel = (const float*)d_in[1];
    const float* w          = (const float*)d_in[2];
    const float* bias       = (const float*)d_in[3];
    const float* gate       = (const float*)d_in[4];
    const float* log_sigma  = (const float*)d_in[5];

    float* out = (float*)d_out;
    float* pv0 = (float*)d_ws;
    int*   pi0 = (int*)((char*)d_ws + 4096);
    float* pv1 = (float*)((char*)d_ws + 8192);
    int*   pi1 = (int*)((char*)d_ws + 12288);

    conv_mfma<<<1024, 256, 0, stream>>>(x, rand_pixel, w, bias, gate, out, pv0, pi0);

    const float* a0 = rand_pixel; const float* a1 = log_sigma; float* a2 = out;
    float* a3 = pv0; int* a4 = pi0; float* a5 = pv1; int* a6 = pi1;
    void* kp[7] = {(void*)&a0, (void*)&a1, (void*)&a2, (void*)&a3,
                   (void*)&a4, (void*)&a5, (void*)&a6};
    hipError_t e = hipLaunchCooperativeKernel((const void*)steps_coop,
                                              dim3(1024), dim3(256), kp, 0, stream);
    if (e != hipSuccess) {
        // fallback: proven per-step path (uses slot 0 in-place)
        for (int s = 0; s < NSTEPS; ++s)
            step_kernel<<<1024, 256, 0, stream>>>(rand_pixel, log_sigma, out, pv0, pi0, s);
    }
}

// Round 3
// 254.329 us; speedup vs baseline: 3.1884x; 3.1884x over previous
//
#include <hip/hip_runtime.h>
#include <hip/hip_bf16.h>

#define NPIX 4096
#define FEAT 128
#define LAT 64
#define BS 64
#define NSTEPS 6

// flat f32 output offsets (log_m_k, log_s_k, c_f, delta, seeds)
#define OFF_LOGM  0u
#define OFF_LOGS  1835008u
#define OFF_CF    3670016u
#define OFF_DELTA 20447232u
#define OFF_SEEDS 20971520u

typedef float f32x4 __attribute__((ext_vector_type(4)));
typedef short s16x8 __attribute__((ext_vector_type(8)));

__device__ __forceinline__ void amax_comb(float& bv, int& bi, float v, int i) {
    if (v > bv || (v == bv && i < bi)) { bv = v; bi = i; }
}

__device__ __forceinline__ short f2bf_rne(float r) {
    __hip_bfloat16 h = __float2bfloat16(r);
    return __builtin_bit_cast(short, h);
}

// split f32 into bf16 hi (truncated -> exact residual) + bf16 lo (RNE of residual)
__device__ __forceinline__ void split2(float v, short& hi, short& lo) {
    unsigned u = __builtin_bit_cast(unsigned, v);
    hi = (short)(u >> 16);
    float hf = __builtin_bit_cast(float, u & 0xFFFF0000u);
    lo = f2bf_rne(v - hf);
}

// ---------------------------------------------------------------------------
// K1: 1x1 conv via split-bf16 MFMA. block = 256 thr (4 waves); each wave:
// all 64 outputs x 64 pixels. grid = 64 batches * 16 tiles (256 px) = 1024.
// Also: zeroes log_s_k[0], emits step-0 argmax partials, zeroes sync counters.
// ---------------------------------------------------------------------------
__global__ __launch_bounds__(256, 2) void conv_mfma(
    const float* __restrict__ x, const float* __restrict__ rand_pixel,
    const float* __restrict__ w, const float* __restrict__ bias,
    const float* __restrict__ gate_p, float* __restrict__ out,
    float* __restrict__ pval, int* __restrict__ pidx, int* __restrict__ cnt)
{
    __shared__ __align__(16) short Whi[64][136];
    __shared__ __align__(16) short Wlo[64][136];
    __shared__ float sbias[64];

    const int tid  = threadIdx.x;
    const int b    = blockIdx.x >> 4;
    const int tile = blockIdx.x & 15;
    const int p0   = tile * 256;
    const int lane = tid & 63;
    const int wv   = tid >> 6;
    const int l15  = lane & 15;
    const int lg   = lane >> 4;

    const float gate = gate_p[0];

    // zero per-batch sync counters (steps kernel runs after this kernel completes)
    if (tile == 0 && wv == 0 && lane < 8) cnt[b * 8 + lane] = 0;

    #pragma unroll
    for (int i = 0; i < 8; ++i) {
        int q = i * 256 + tid;
        int o = q >> 5;
        int f = (q & 31) * 4;
        float4 wq = *(const float4*)(w + o * 128 + f);
        short h0, l0, h1, l1, h2, l2, h3, l3;
        split2(gate * wq.x, h0, l0);
        split2(gate * wq.y, h1, l1);
        split2(gate * wq.z, h2, l2);
        split2(gate * wq.w, h3, l3);
        *(short4*)&Whi[o][f] = make_short4(h0, h1, h2, h3);
        *(short4*)&Wlo[o][f] = make_short4(l0, l1, l2, l3);
    }
    if (tid < 64) sbias[tid] = gate * bias[tid];
    __syncthreads();

    f32x4 acc[4][4];
    #pragma unroll
    for (int og = 0; og < 4; ++og)
        #pragma unroll
        for (int pg = 0; pg < 4; ++pg)
            acc[og][pg] = (f32x4){0.f, 0.f, 0.f, 0.f};

    const float* xb = x + (size_t)b * FEAT * NPIX + p0 + wv * 64;

    #pragma unroll
    for (int kc = 0; kc < 4; ++kc) {
        s16x8 Ah[4], Al[4];
        #pragma unroll
        for (int og = 0; og < 4; ++og) {
            Ah[og] = *(const s16x8*)&Whi[og * 16 + l15][kc * 32 + lg * 8];
            Al[og] = *(const s16x8*)&Wlo[og * 16 + l15][kc * 32 + lg * 8];
        }
        #pragma unroll
        for (int pg = 0; pg < 4; ++pg) {
            const float* xp = xb + pg * 16 + l15;
            const int fb = kc * 32 + lg * 8;
            float xv[8];
            #pragma unroll
            for (int e = 0; e < 8; ++e)
                xv[e] = xp[(size_t)(fb + e) * NPIX];
            s16x8 Bh, Bl;
            #pragma unroll
            for (int e = 0; e < 8; ++e) {
                short h, l;
                split2(xv[e], h, l);
                Bh[e] = h; Bl[e] = l;
            }
            #pragma unroll
            for (int og = 0; og < 4; ++og) {
                acc[og][pg] = __builtin_amdgcn_mfma_f32_16x16x32_bf16(Ah[og], Bh, acc[og][pg], 0, 0, 0);
                acc[og][pg] = __builtin_amdgcn_mfma_f32_16x16x32_bf16(Ah[og], Bl, acc[og][pg], 0, 0, 0);
                acc[og][pg] = __builtin_amdgcn_mfma_f32_16x16x32_bf16(Al[og], Bh, acc[og][pg], 0, 0, 0);
            }
        }
    }

    float* cf = out + OFF_CF + (size_t)b * LAT * NPIX;
    #pragma unroll
    for (int og = 0; og < 4; ++og) {
        #pragma unroll
        for (int pg = 0; pg < 4; ++pg) {
            #pragma unroll
            for (int r = 0; r < 4; ++r) {
                int o = og * 16 + lg * 4 + r;
                int p = p0 + wv * 64 + pg * 16 + l15;
                float v = acc[og][pg][r] + sbias[o];
                if (o == 62) {
                    out[OFF_DELTA + ((size_t)b * 2 + 0) * NPIX + p] = v;
                    v += (float)(-1.0 + 2.0 * (double)(p >> 6) / 63.0);
                } else if (o == 63) {
                    out[OFF_DELTA + ((size_t)b * 2 + 1) * NPIX + p] = v;
                    v += (float)(-1.0 + 2.0 * (double)(p & 63) / 63.0);
                }
                cf[(size_t)o * NPIX + p] = v;
            }
        }
    }

    if (wv == 0) {
        *(float4*)(out + OFF_LOGS + (size_t)b * NPIX + p0 + lane * 4) =
            make_float4(0.f, 0.f, 0.f, 0.f);
        float4 rv = *(const float4*)(rand_pixel + (size_t)b * NPIX + p0 + lane * 4);
        int pb = p0 + lane * 4;
        float bv = rv.x; int bi = pb;
        if (rv.y > bv) { bv = rv.y; bi = pb + 1; }
        if (rv.z > bv) { bv = rv.z; bi = pb + 2; }
        if (rv.w > bv) { bv = rv.w; bi = pb + 3; }
        #pragma unroll
        for (int off = 32; off > 0; off >>= 1) {
            float ov = __shfl_down(bv, off, 64);
            int   oi = __shfl_down(bi, off, 64);
            amax_comb(bv, bi, ov, oi);
        }
        if (lane == 0) { pval[blockIdx.x] = bv; pidx[blockIdx.x] = bi; }
    }
}

// ---------------------------------------------------------------------------
// K2: all 6 steps fused, c_f in registers, hand-rolled PER-BATCH sync
// (no cg::grid_group -> no function call -> no forced spill; sync waits only
// for the 16 blocks of the same batch). Launched cooperatively only to
// guarantee co-residency of all 1024 blocks (4 blocks/CU x 256 CU).
// pv/pi layout: [step][batch][16 tiles]; cnt: [batch][8].
// ---------------------------------------------------------------------------
__global__ __launch_bounds__(256, 4) void steps_fused(
    const float* __restrict__ rand_pixel, const float* __restrict__ log_sigma_p,
    float* __restrict__ out, float* pv, int* pi, int* cnt)
{
    __shared__ float s_mv[16];
    __shared__ int   s_mi[16];
    __shared__ float s_seed[LAT];
    __shared__ float s_rv[4];
    __shared__ int   s_ri[4];

    const int tid  = threadIdx.x;
    const int b    = blockIdx.x >> 4;
    const int tile = blockIdx.x & 15;
    const int p    = tile * 256 + tid;

    const float* cf = out + OFF_CF + (size_t)b * LAT * NPIX;

    // pixel's 64 channels -> registers (static indexing only)
    float cr[LAT];
    #pragma unroll
    for (int c = 0; c < LAT; ++c) cr[c] = cf[(size_t)c * NPIX + p];

    const float rp    = rand_pixel[(size_t)b * NPIX + p];
    const float sigma = expf(log_sigma_p[0]);
    float ls = 0.f;

    #pragma unroll 1
    for (int s = 0; s < NSTEPS; ++s) {
        // wait for this batch's 16 partials (step 0: produced by conv kernel)
        if (s > 0) {
            if (tid == 0) {
                while (__hip_atomic_load(&cnt[b * 8 + s], __ATOMIC_ACQUIRE,
                                         __HIP_MEMORY_SCOPE_AGENT) < 16)
                    __builtin_amdgcn_s_sleep(1);
            }
            __syncthreads();
        }
        if (tid < 16) {
            s_mv[tid] = __hip_atomic_load(&pv[(s * BS + b) * 16 + tid],
                                          __ATOMIC_RELAXED, __HIP_MEMORY_SCOPE_AGENT);
            s_mi[tid] = __hip_atomic_load(&pi[(s * BS + b) * 16 + tid],
                                          __ATOMIC_RELAXED, __HIP_MEMORY_SCOPE_AGENT);
        }
        __syncthreads();

        float bv = -1.0f; int bi = 0;
        #pragma unroll
        for (int k = 0; k < 16; ++k) amax_comb(bv, bi, s_mv[k], s_mi[k]);

        if (tid < LAT) s_seed[tid] = cf[(size_t)tid * NPIX + bi];
        __syncthreads();
        if (tile == 0 && tid < LAT)
            out[OFF_SEEDS + ((size_t)s * BS + b) * LAT + tid] = s_seed[tid];

        float d2 = 0.f;
        #pragma unroll
        for (int c = 0; c < LAT; ++c) {
            float d = cr[c] - s_seed[c];
            d2 = fmaf(d, d, d2);
        }
        float dist  = sqrtf(fminf(fmaxf(d2, 1e-10f), 1e10f));
        float alpha = expf(-dist / sigma);
        alpha = fminf(fmaxf(alpha, 0.01f), 0.99f);
        float lm  = ls + logf(alpha);
        float lsn = ls + log1pf(-alpha);

        out[OFF_LOGM + ((size_t)s * BS + b) * NPIX + p]       = lm;
        out[OFF_LOGS + ((size_t)(s + 1) * BS + b) * NPIX + p] = lsn;
        ls = lsn;

        if (s == NSTEPS - 1) {
            out[OFF_LOGM + ((size_t)NSTEPS * BS + b) * NPIX + p] = lsn;
        } else {
            // produce next step's partial; publish + release-increment counter
            float prob = rp * expf(lsn);
            int   idx  = p;
            #pragma unroll
            for (int off = 32; off > 0; off >>= 1) {
                float ov = __shfl_down(prob, off, 64);
                int   oi = __shfl_down(idx, off, 64);
                amax_comb(prob, idx, ov, oi);
            }
            int lane = tid & 63, wid = tid >> 6;
            if (lane == 0) { s_rv[wid] = prob; s_ri[wid] = idx; }
            __syncthreads();
            if (tid == 0) {
                float fb = s_rv[0]; int fi = s_ri[0];
                #pragma unroll
                for (int k = 1; k < 4; ++k) amax_comb(fb, fi, s_rv[k], s_ri[k]);
                __hip_atomic_store(&pv[((s + 1) * BS + b) * 16 + tile], fb,
                                   __ATOMIC_RELAXED, __HIP_MEMORY_SCOPE_AGENT);
                __hip_atomic_store(&pi[((s + 1) * BS + b) * 16 + tile], fi,
                                   __ATOMIC_RELAXED, __HIP_MEMORY_SCOPE_AGENT);
                __hip_atomic_fetch_add(&cnt[b * 8 + s + 1], 1,
                                       __ATOMIC_RELEASE, __HIP_MEMORY_SCOPE_AGENT);
            }
        }
    }
}

// ---------------------------------------------------------------------------
// Fallback: per-step kernel (proven path) if cooperative launch unavailable.
// Uses pv/pi step-0 slots in place.
// ---------------------------------------------------------------------------
__global__ __launch_bounds__(256, 4) void step_kernel(
    const float* __restrict__ rand_pixel, const float* __restrict__ log_sigma_p,
    float* __restrict__ out, float* __restrict__ pval, int* __restrict__ pidx,
    int step)
{
    __shared__ float s_seed[LAT];
    __shared__ float s_rv[4];
    __shared__ int   s_ri[4];

    const int tid  = threadIdx.x;
    const int b    = blockIdx.x >> 4;
    const int tile = blockIdx.x & 15;
    const int p    = tile * 256 + tid;

    float bv = -1.0f; int bi = 0;
    #pragma unroll
    for (int k = 0; k < 16; ++k) amax_comb(bv, bi, pval[b * 16 + k], pidx[b * 16 + k]);

    const float* cf = out + OFF_CF + (size_t)b * LAT * NPIX;
    if (tid < LAT) s_seed[tid] = cf[(size_t)tid * NPIX + bi];
    __syncthreads();

    if (tile == 0 && tid < LAT)
        out[OFF_SEEDS + ((size_t)step * BS + b) * LAT + tid] = s_seed[tid];

    float d2 = 0.f;
    #pragma unroll 16
    for (int c = 0; c < LAT; ++c) {
        float d = cf[(size_t)c * NPIX + p] - s_seed[c];
        d2 = fmaf(d, d, d2);
    }
    float dist  = sqrtf(fminf(fmaxf(d2, 1e-10f), 1e10f));
    float sigma = expf(log_sigma_p[0]);
    float alpha = expf(-dist / sigma);
    alpha = fminf(fmaxf(alpha, 0.01f), 0.99f);

    float ls  = out[OFF_LOGS + ((size_t)step * BS + b) * NPIX + p];
    float lm  = ls + logf(alpha);
    float lsn = ls + log1pf(-alpha);

    out[OFF_LOGM + ((size_t)step * BS + b) * NPIX + p]       = lm;
    out[OFF_LOGS + ((size_t)(step + 1) * BS + b) * NPIX + p] = lsn;
    if (step == NSTEPS - 1)
        out[OFF_LOGM + ((size_t)NSTEPS * BS + b) * NPIX + p] = lsn;

    if (step < NSTEPS - 1) {
        float prob = rand_pixel[(size_t)b * NPIX + p] * expf(lsn);
        int   idx  = p;
        #pragma unroll
        for (int off = 32; off > 0; off >>= 1) {
            float ov = __shfl_down(prob, off, 64);
            int   oi = __shfl_down(idx, off, 64);
            amax_comb(prob, idx, ov, oi);
        }
        int lane = tid & 63, wid = tid >> 6;
        if (lane == 0) { s_rv[wid] = prob; s_ri[wid] = idx; }
        __syncthreads();
        if (tid == 0) {
            float fb = s_rv[0]; int fi = s_ri[0];
            #pragma unroll
            for (int k = 1; k < 4; ++k) amax_comb(fb, fi, s_rv[k], s_ri[k]);
            pval[blockIdx.x] = fb; pidx[blockIdx.x] = fi;
        }
    }
}

extern "C" void kernel_launch(void* const* d_in, const int* in_sizes, int n_in,
                              void* d_out, int out_size, void* d_ws, size_t ws_size,
                              hipStream_t stream) {
    const float* x          = (const float*)d_in[0];
    const float* rand_pixel = (const float*)d_in[1];
    const float* w          = (const float*)d_in[2];
    const float* bias       = (const float*)d_in[3];
    const float* gate       = (const float*)d_in[4];
    const float* log_sigma  = (const float*)d_in[5];

    float* out = (float*)d_out;
    // ws layout: pv [6][64][16] f32 (24576B) | pi [6][64][16] i32 (24576B) | cnt [64][8] i32 (2048B)
    float* pv  = (float*)d_ws;
    int*   pi  = (int*)((char*)d_ws + 24576);
    int*   cnt = (int*)((char*)d_ws + 49152);

    conv_mfma<<<1024, 256, 0, stream>>>(x, rand_pixel, w, bias, gate, out, pv, pi, cnt);

    const float* a0 = rand_pixel; const float* a1 = log_sigma; float* a2 = out;
    float* a3 = pv; int* a4 = pi; int* a5 = cnt;
    void* kp[6] = {(void*)&a0, (void*)&a1, (void*)&a2, (void*)&a3, (void*)&a4, (void*)&a5};
    hipError_t e = hipLaunchCooperativeKernel((const void*)steps_fused,
                                              dim3(1024), dim3(256), kp, 0, stream);
    if (e != hipSuccess) {
        for (int s = 0; s < NSTEPS; ++s)
            step_kernel<<<1024, 256, 0, stream>>>(rand_pixel, log_sigma, out, pv, pi, s);
    }
}

// Round 4
// 134.320 us; speedup vs baseline: 6.0371x; 1.8935x over previous
//
#include <hip/hip_runtime.h>
#include <hip/hip_bf16.h>

#define NPIX 4096
#define FEAT 128
#define LAT 64
#define BS 64
#define NSTEPS 6

// flat f32 output offsets (log_m_k, log_s_k, c_f, delta, seeds)
#define OFF_LOGM  0u
#define OFF_LOGS  1835008u
#define OFF_CF    3670016u
#define OFF_DELTA 20447232u
#define OFF_SEEDS 20971520u

typedef float f32x4 __attribute__((ext_vector_type(4)));
typedef short s16x8 __attribute__((ext_vector_type(8)));

__device__ __forceinline__ void amax_comb(float& bv, int& bi, float v, int i) {
    if (v > bv || (v == bv && i < bi)) { bv = v; bi = i; }
}

__device__ __forceinline__ short f2bf_rne(float r) {
    __hip_bfloat16 h = __float2bfloat16(r);
    return __builtin_bit_cast(short, h);
}

__device__ __forceinline__ void split2(float v, short& hi, short& lo) {
    unsigned u = __builtin_bit_cast(unsigned, v);
    hi = (short)(u >> 16);
    float hf = __builtin_bit_cast(float, u & 0xFFFF0000u);
    lo = f2bf_rne(v - hf);
}

// ---------------------------------------------------------------------------
// K1: 1x1 conv via split-bf16 MFMA (unchanged from round 3 — proven).
// grid = 64 batches * 16 tiles(256px) = 1024 blocks x 256 thr.
// Also zeroes log_s_k[0], emits step-0 argmax partials, zeroes sync counters.
// ---------------------------------------------------------------------------
__global__ __launch_bounds__(256, 2) void conv_mfma(
    const float* __restrict__ x, const float* __restrict__ rand_pixel,
    const float* __restrict__ w, const float* __restrict__ bias,
    const float* __restrict__ gate_p, float* __restrict__ out,
    float* __restrict__ pval, int* __restrict__ pidx, int* __restrict__ cnt)
{
    __shared__ __align__(16) short Whi[64][136];
    __shared__ __align__(16) short Wlo[64][136];
    __shared__ float sbias[64];

    const int tid  = threadIdx.x;
    const int b    = blockIdx.x >> 4;
    const int tile = blockIdx.x & 15;
    const int p0   = tile * 256;
    const int lane = tid & 63;
    const int wv   = tid >> 6;
    const int l15  = lane & 15;
    const int lg   = lane >> 4;

    const float gate = gate_p[0];

    if (tile == 0 && wv == 0 && lane < 8) cnt[b * 8 + lane] = 0;

    #pragma unroll
    for (int i = 0; i < 8; ++i) {
        int q = i * 256 + tid;
        int o = q >> 5;
        int f = (q & 31) * 4;
        float4 wq = *(const float4*)(w + o * 128 + f);
        short h0, l0, h1, l1, h2, l2, h3, l3;
        split2(gate * wq.x, h0, l0);
        split2(gate * wq.y, h1, l1);
        split2(gate * wq.z, h2, l2);
        split2(gate * wq.w, h3, l3);
        *(short4*)&Whi[o][f] = make_short4(h0, h1, h2, h3);
        *(short4*)&Wlo[o][f] = make_short4(l0, l1, l2, l3);
    }
    if (tid < 64) sbias[tid] = gate * bias[tid];
    __syncthreads();

    f32x4 acc[4][4];
    #pragma unroll
    for (int og = 0; og < 4; ++og)
        #pragma unroll
        for (int pg = 0; pg < 4; ++pg)
            acc[og][pg] = (f32x4){0.f, 0.f, 0.f, 0.f};

    const float* xb = x + (size_t)b * FEAT * NPIX + p0 + wv * 64;

    #pragma unroll
    for (int kc = 0; kc < 4; ++kc) {
        s16x8 Ah[4], Al[4];
        #pragma unroll
        for (int og = 0; og < 4; ++og) {
            Ah[og] = *(const s16x8*)&Whi[og * 16 + l15][kc * 32 + lg * 8];
            Al[og] = *(const s16x8*)&Wlo[og * 16 + l15][kc * 32 + lg * 8];
        }
        #pragma unroll
        for (int pg = 0; pg < 4; ++pg) {
            const float* xp = xb + pg * 16 + l15;
            const int fb = kc * 32 + lg * 8;
            float xv[8];
            #pragma unroll
            for (int e = 0; e < 8; ++e)
                xv[e] = xp[(size_t)(fb + e) * NPIX];
            s16x8 Bh, Bl;
            #pragma unroll
            for (int e = 0; e < 8; ++e) {
                short h, l;
                split2(xv[e], h, l);
                Bh[e] = h; Bl[e] = l;
            }
            #pragma unroll
            for (int og = 0; og < 4; ++og) {
                acc[og][pg] = __builtin_amdgcn_mfma_f32_16x16x32_bf16(Ah[og], Bh, acc[og][pg], 0, 0, 0);
                acc[og][pg] = __builtin_amdgcn_mfma_f32_16x16x32_bf16(Ah[og], Bl, acc[og][pg], 0, 0, 0);
                acc[og][pg] = __builtin_amdgcn_mfma_f32_16x16x32_bf16(Al[og], Bh, acc[og][pg], 0, 0, 0);
            }
        }
    }

    float* cf = out + OFF_CF + (size_t)b * LAT * NPIX;
    #pragma unroll
    for (int og = 0; og < 4; ++og) {
        #pragma unroll
        for (int pg = 0; pg < 4; ++pg) {
            #pragma unroll
            for (int r = 0; r < 4; ++r) {
                int o = og * 16 + lg * 4 + r;
                int p = p0 + wv * 64 + pg * 16 + l15;
                float v = acc[og][pg][r] + sbias[o];
                if (o == 62) {
                    out[OFF_DELTA + ((size_t)b * 2 + 0) * NPIX + p] = v;
                    v += (float)(-1.0 + 2.0 * (double)(p >> 6) / 63.0);
                } else if (o == 63) {
                    out[OFF_DELTA + ((size_t)b * 2 + 1) * NPIX + p] = v;
                    v += (float)(-1.0 + 2.0 * (double)(p & 63) / 63.0);
                }
                cf[(size_t)o * NPIX + p] = v;
            }
        }
    }

    if (wv == 0) {
        *(float4*)(out + OFF_LOGS + (size_t)b * NPIX + p0 + lane * 4) =
            make_float4(0.f, 0.f, 0.f, 0.f);
        float4 rv = *(const float4*)(rand_pixel + (size_t)b * NPIX + p0 + lane * 4);
        int pb = p0 + lane * 4;
        float bv = rv.x; int bi = pb;
        if (rv.y > bv) { bv = rv.y; bi = pb + 1; }
        if (rv.z > bv) { bv = rv.z; bi = pb + 2; }
        if (rv.w > bv) { bv = rv.w; bi = pb + 3; }
        #pragma unroll
        for (int off = 32; off > 0; off >>= 1) {
            float ov = __shfl_down(bv, off, 64);
            int   oi = __shfl_down(bi, off, 64);
            amax_comb(bv, bi, ov, oi);
        }
        if (lane == 0) { pval[blockIdx.x] = bv; pidx[blockIdx.x] = bi; }
    }
}

// named-register c_f: 16 x f32x4 per thread
#define REP16(OP) OP(0) OP(1) OP(2) OP(3) OP(4) OP(5) OP(6) OP(7) \
                  OP(8) OP(9) OP(10) OP(11) OP(12) OP(13) OP(14) OP(15)

// ---------------------------------------------------------------------------
// K2: fused 6-step clustering. Block = 1024 thr = 1024 px (1 px/thread),
// grid = 256 (64 batches x 4 tiles) = 1 block/CU. c_f held in 16 NAMED f32x4
// registers; d2 via |c|^2 + |s|^2 - 2 c.s (|c|^2 precomputed). Per-batch
// quorum-4 spin sync (agent-scope atomics). pv/pi: [step][batch][16].
// ---------------------------------------------------------------------------
__global__ __launch_bounds__(1024) void steps_fused(
    const float* __restrict__ rand_pixel, const float* __restrict__ log_sigma_p,
    float* __restrict__ out, float* pv, int* pi, int* cnt)
{
    __shared__ float s_mv[16];
    __shared__ int   s_mi[16];
    __shared__ __align__(16) float s_seed[LAT];
    __shared__ float s_rv[16];
    __shared__ int   s_ri[16];

    const int tid  = threadIdx.x;
    const int b    = blockIdx.x >> 2;
    const int tile = blockIdx.x & 3;
    const int p    = tile * 1024 + tid;

    const float* cfb = out + OFF_CF + (size_t)b * LAT * NPIX;

#define DECLR(i) f32x4 r##i;
    REP16(DECLR)
#define LOADR(i) r##i = (f32x4){ cfb[(size_t)(4*i+0)*NPIX + p], cfb[(size_t)(4*i+1)*NPIX + p], \
                                 cfb[(size_t)(4*i+2)*NPIX + p], cfb[(size_t)(4*i+3)*NPIX + p] };
    REP16(LOADR)

    f32x4 aq = r0 * r0;
#define SQR(i) aq += r##i * r##i;
    SQR(1) SQR(2) SQR(3) SQR(4) SQR(5) SQR(6) SQR(7)
    SQR(8) SQR(9) SQR(10) SQR(11) SQR(12) SQR(13) SQR(14) SQR(15)
    const float cr2 = aq[0] + aq[1] + aq[2] + aq[3];

    const float rp    = rand_pixel[(size_t)b * NPIX + p];
    const float sigma = expf(log_sigma_p[0]);
    float ls = 0.f;

    #pragma unroll 1
    for (int s = 0; s < NSTEPS; ++s) {
        if (s > 0) {
            if (tid == 0) {
                while (__hip_atomic_load(&cnt[b * 8 + s], __ATOMIC_ACQUIRE,
                                         __HIP_MEMORY_SCOPE_AGENT) < 4)
                    __builtin_amdgcn_s_sleep(2);
            }
            __syncthreads();
        }
        const int nmerge = (s == 0) ? 16 : 4;
        if (tid < nmerge) {
            s_mv[tid] = __hip_atomic_load(&pv[(s * BS + b) * 16 + tid],
                                          __ATOMIC_RELAXED, __HIP_MEMORY_SCOPE_AGENT);
            s_mi[tid] = __hip_atomic_load(&pi[(s * BS + b) * 16 + tid],
                                          __ATOMIC_RELAXED, __HIP_MEMORY_SCOPE_AGENT);
        }
        __syncthreads();

        float bv = -1.0f; int bi = 0;
        for (int k = 0; k < nmerge; ++k) amax_comb(bv, bi, s_mv[k], s_mi[k]);

        if (tid < LAT) s_seed[tid] = cfb[(size_t)tid * NPIX + bi];
        __syncthreads();
        if (tile == 0 && tid < LAT)
            out[OFF_SEEDS + ((size_t)s * BS + b) * LAT + tid] = s_seed[tid];

        // d2 = |c|^2 + |s|^2 - 2 c.s
        f32x4 dacc = (f32x4){0.f, 0.f, 0.f, 0.f};
        f32x4 sacc = (f32x4){0.f, 0.f, 0.f, 0.f};
#define DOT(i) { f32x4 sv = *(const f32x4*)&s_seed[4*i]; dacc += r##i * sv; sacc += sv * sv; }
        REP16(DOT)
        float dot = dacc[0] + dacc[1] + dacc[2] + dacc[3];
        float s2  = sacc[0] + sacc[1] + sacc[2] + sacc[3];
        float d2  = cr2 + s2 - 2.0f * dot;

        float dist  = sqrtf(fminf(fmaxf(d2, 1e-10f), 1e10f));
        float alpha = expf(-dist / sigma);
        alpha = fminf(fmaxf(alpha, 0.01f), 0.99f);
        float lm  = ls + logf(alpha);
        float lsn = ls + log1pf(-alpha);

        out[OFF_LOGM + ((size_t)s * BS + b) * NPIX + p]       = lm;
        out[OFF_LOGS + ((size_t)(s + 1) * BS + b) * NPIX + p] = lsn;
        ls = lsn;

        if (s == NSTEPS - 1) {
            out[OFF_LOGM + ((size_t)NSTEPS * BS + b) * NPIX + p] = lsn;
        } else {
            float prob = rp * expf(lsn);
            int   idx  = p;
            #pragma unroll
            for (int off = 32; off > 0; off >>= 1) {
                float ov = __shfl_down(prob, off, 64);
                int   oi = __shfl_down(idx, off, 64);
                amax_comb(prob, idx, ov, oi);
            }
            int lane = tid & 63, wid = tid >> 6;
            if (lane == 0) { s_rv[wid] = prob; s_ri[wid] = idx; }
            __syncthreads();
            if (tid == 0) {
                float fb = s_rv[0]; int fi = s_ri[0];
                #pragma unroll
                for (int k = 1; k < 16; ++k) amax_comb(fb, fi, s_rv[k], s_ri[k]);
                __hip_atomic_store(&pv[((s + 1) * BS + b) * 16 + tile], fb,
                                   __ATOMIC_RELAXED, __HIP_MEMORY_SCOPE_AGENT);
                __hip_atomic_store(&pi[((s + 1) * BS + b) * 16 + tile], fi,
                                   __ATOMIC_RELAXED, __HIP_MEMORY_SCOPE_AGENT);
                __hip_atomic_fetch_add(&cnt[b * 8 + s + 1], 1,
                                       __ATOMIC_RELEASE, __HIP_MEMORY_SCOPE_AGENT);
            }
        }
    }
}

// ---------------------------------------------------------------------------
// Fallback: per-step kernel, same 1024-thr geometry & math, kernel-boundary
// sync instead of spin. pv/pi layout identical.
// ---------------------------------------------------------------------------
__global__ __launch_bounds__(1024) void step_kernel(
    const float* __restrict__ rand_pixel, const float* __restrict__ log_sigma_p,
    float* __restrict__ out, float* pv, int* pi, int step)
{
    __shared__ float s_mv[16];
    __shared__ int   s_mi[16];
    __shared__ __align__(16) float s_seed[LAT];
    __shared__ float s_rv[16];
    __shared__ int   s_ri[16];

    const int tid  = threadIdx.x;
    const int b    = blockIdx.x >> 2;
    const int tile = blockIdx.x & 3;
    const int p    = tile * 1024 + tid;

    const float* cfb = out + OFF_CF + (size_t)b * LAT * NPIX;

    const int nmerge = (step == 0) ? 16 : 4;
    if (tid < nmerge) { s_mv[tid] = pv[(step * BS + b) * 16 + tid];
                        s_mi[tid] = pi[(step * BS + b) * 16 + tid]; }
    __syncthreads();
    float bv = -1.0f; int bi = 0;
    for (int k = 0; k < nmerge; ++k) amax_comb(bv, bi, s_mv[k], s_mi[k]);

    if (tid < LAT) s_seed[tid] = cfb[(size_t)tid * NPIX + bi];
    __syncthreads();
    if (tile == 0 && tid < LAT)
        out[OFF_SEEDS + ((size_t)step * BS + b) * LAT + tid] = s_seed[tid];

    float d2 = 0.f;
    #pragma unroll
    for (int c = 0; c < LAT; ++c) {
        float d = cfb[(size_t)c * NPIX + p] - s_seed[c];
        d2 = fmaf(d, d, d2);
    }
    float dist  = sqrtf(fminf(fmaxf(d2, 1e-10f), 1e10f));
    float sigma = expf(log_sigma_p[0]);
    float alpha = expf(-dist / sigma);
    alpha = fminf(fmaxf(alpha, 0.01f), 0.99f);

    float ls  = out[OFF_LOGS + ((size_t)step * BS + b) * NPIX + p];
    float lm  = ls + logf(alpha);
    float lsn = ls + log1pf(-alpha);

    out[OFF_LOGM + ((size_t)step * BS + b) * NPIX + p]       = lm;
    out[OFF_LOGS + ((size_t)(step + 1) * BS + b) * NPIX + p] = lsn;
    if (step == NSTEPS - 1)
        out[OFF_LOGM + ((size_t)NSTEPS * BS + b) * NPIX + p] = lsn;

    if (step < NSTEPS - 1) {
        float prob = rand_pixel[(size_t)b * NPIX + p] * expf(lsn);
        int   idx  = p;
        #pragma unroll
        for (int off = 32; off > 0; off >>= 1) {
            float ov = __shfl_down(prob, off, 64);
            int   oi = __shfl_down(idx, off, 64);
            amax_comb(prob, idx, ov, oi);
        }
        int lane = tid & 63, wid = tid >> 6;
        if (lane == 0) { s_rv[wid] = prob; s_ri[wid] = idx; }
        __syncthreads();
        if (tid == 0) {
            float fb = s_rv[0]; int fi = s_ri[0];
            #pragma unroll
            for (int k = 1; k < 16; ++k) amax_comb(fb, fi, s_rv[k], s_ri[k]);
            pv[((step + 1) * BS + b) * 16 + tile] = fb;
            pi[((step + 1) * BS + b) * 16 + tile] = fi;
        }
    }
}

extern "C" void kernel_launch(void* const* d_in, const int* in_sizes, int n_in,
                              void* d_out, int out_size, void* d_ws, size_t ws_size,
                              hipStream_t stream) {
    const float* x          = (const float*)d_in[0];
    const float* rand_pixel = (const float*)d_in[1];
    const float* w          = (const float*)d_in[2];
    const float* bias       = (const float*)d_in[3];
    const float* gate       = (const float*)d_in[4];
    const float* log_sigma  = (const float*)d_in[5];

    float* out = (float*)d_out;
    // ws: pv [6][64][16] f32 | pi [6][64][16] i32 | cnt [64][8] i32
    float* pv  = (float*)d_ws;
    int*   pi  = (int*)((char*)d_ws + 24576);
    int*   cnt = (int*)((char*)d_ws + 49152);

    conv_mfma<<<1024, 256, 0, stream>>>(x, rand_pixel, w, bias, gate, out, pv, pi, cnt);

    const float* a0 = rand_pixel; const float* a1 = log_sigma; float* a2 = out;
    float* a3 = pv; int* a4 = pi; int* a5 = cnt;
    void* kp[6] = {(void*)&a0, (void*)&a1, (void*)&a2, (void*)&a3, (void*)&a4, (void*)&a5};
    hipError_t e = hipLaunchCooperativeKernel((const void*)steps_fused,
                                              dim3(256), dim3(1024), kp, 0, stream);
    if (e != hipSuccess) {
        for (int s = 0; s < NSTEPS; ++s)
            step_kernel<<<256, 1024, 0, stream>>>(rand_pixel, log_sigma, out, pv, pi, s);
    }
}